// Round 6
// baseline (217.677 us; speedup 1.0000x reference)
//
#include <hip/hip_runtime.h>
#include <hip/hip_bf16.h>

typedef unsigned short u16;
typedef unsigned int   u32;
typedef unsigned long long u64;

#define BATCH 4096
#define IDIM  1024
#define ODIM  1024
#define NDEG  9                 // degree 8 -> 9 basis terms
#define KTOT  (IDIM * NDEG)     // 9216
#define KHALF (KTOT / 2)        // 4608

typedef __attribute__((ext_vector_type(8))) short short8_t;   // 8 bf16 = 4 VGPRs
typedef __attribute__((ext_vector_type(4))) float f32x4;

// s_waitcnt simm16 (gfx9/CDNA): vmcnt[3:0]|expcnt<<4|lgkmcnt<<8|vmcnt[5:4]<<14
#define WAIT_VM16 0x4F70        // vmcnt(16), lgkm/exp unconstrained
#define WAIT_VM0  0x0F70        // vmcnt(0)

// round-to-nearest-even f32 -> bf16
__device__ __forceinline__ u16 f2bf(float f) {
    union { float f; u32 u; } v; v.f = f;
    u32 r = v.u + 0x7FFFu + ((v.u >> 16) & 1u);
    return (u16)(r >> 16);
}
__device__ __forceinline__ u32 pack2bf(float lo, float hi) {
    return (u32)f2bf(lo) | ((u32)f2bf(hi) << 16);
}

// async 16B global -> LDS (wave-uniform LDS base + lane*16)
__device__ __forceinline__ void gl_lds16(const u16* g, u16* l) {
    __builtin_amdgcn_global_load_lds(
        (const __attribute__((address_space(1))) void*)g,
        (__attribute__((address_space(3))) void*)l,
        16, 0, 0);
}

// ---------------------------------------------------------------------------
// Fused prep (single dispatch, block-role split):
//   blocks [0, 1024)    : Bt[o][k=d*1024+i] <- coeffs[i][o][d] (LDS transpose)
//   blocks [1024, 9216) : A[b][k=d*1024+i]  <- V_d(tanh(x[b,i]))
// ---------------------------------------------------------------------------
#define PB_TI 128
#define PB_TO 8
#define PB_J  (PB_TO * NDEG)    // 72
#define PB_LS 132               // LDS row stride (u16): 264 B, u64-aligned rows

#define NB_B   1024
#define NB_A   8192

__global__ void prep_kernel(const float* __restrict__ x,
                            const float* __restrict__ c,
                            u16* __restrict__ A, u16* __restrict__ Bt) {
    __shared__ u16 lds[PB_J * PB_LS];             // 19 KB (B-blocks only)
    const int bb  = blockIdx.x;
    const int tid = threadIdx.x;

    if (bb < NB_B) {
        const int i0 = (bb & 7) * PB_TI;
        const int o0 = (bb >> 3) * PB_TO;
        const float* src = c + (size_t)i0 * (ODIM * NDEG) + (size_t)o0 * NDEG;
#pragma unroll
        for (int t = 0; t < 36; ++t) {
            int f  = t * 256 + tid;
            int ii = f / PB_J;
            int j  = f - ii * PB_J;
            float v = src[(size_t)ii * (ODIM * NDEG) + j];
            lds[j * PB_LS + ii] = f2bf(v);
        }
        __syncthreads();
#pragma unroll
        for (int t = 0; t < 9; ++t) {
            int g   = t * 256 + tid;
            int j   = g >> 5;
            int ii4 = (g & 31) << 2;
            int o   = j / NDEG;
            int d   = j - o * NDEG;
            u64 v = *(const u64*)(lds + j * PB_LS + ii4);
            *(u64*)(Bt + (size_t)(o0 + o) * KTOT + d * 1024 + i0 + ii4) = v;
        }
    } else {
        int t  = (bb - NB_B) * 256 + tid;
        int b  = t >> 9;
        int i2 = (t & 511) << 1;
        float2 xv = ((const float2*)x)[t];
        float t0 = tanhf(xv.x), t1 = tanhf(xv.y);
        u32* dst = (u32*)(A + (size_t)b * KTOT + i2);
        float a0 = 2.0f, a1 = 2.0f;
        float b0 = t0,  b1 = t1;
        dst[0]   = pack2bf(2.0f, 2.0f);
        dst[512] = pack2bf(t0, t1);
#pragma unroll
        for (int d = 2; d < NDEG; ++d) {
            float n0 = t0 * b0 + a0;
            float n1 = t1 * b1 + a1;
            dst[(size_t)d * 512] = pack2bf(n0, n1);
            a0 = b0; b0 = n0; a1 = b1; b1 = n1;
        }
    }
}

// ---------------------------------------------------------------------------
// Barrier-free GEMM: 1 wave per block, 64x64 output quadrant, self-paced
// double-buffered global_load_lds staging with EXPLICIT per-wave
// s_waitcnt vmcnt(16): waits only for the current tile's 16 DMA ops while
// the 16 prefetches for the next tile stay in flight (m135 semantics).
// R5 bug: no wait at all between DMA and ds_read -> race; fixed here.
// grid = 2048 blocks (5/CU at 32 KB LDS); per-wave stalls uncorrelated.
// Pane layout: [row 0..63][8 chunks x 16B], physical chunk = c ^ (row&7).
// XCD swizzle: per XCD one 1024-row x 512-col patch at half-K.
// ---------------------------------------------------------------------------
__global__ __launch_bounds__(64, 2)
void gemm_kernel(const u16* __restrict__ A, const u16* __restrict__ B,
                 float* __restrict__ P) {
    __shared__ __align__(16) u16 lds[2][2][4096];   // [buf][A/B][64*64] = 32 KB

    const int lane = threadIdx.x;
    const int quad = lane >> 4;
    const int l15  = lane & 15;

    const int bid = blockIdx.x;                     // 0..2047
    const int xcd = bid & 7;
    const int loc = bid >> 3;                       // 0..255
    const int z   = loc >> 7;
    const int lv  = loc & 127;
    const int bm  = ((xcd & 3) << 4) | (lv & 15);   // 0..63
    const int bn  = ((xcd >> 2) << 3) | (lv >> 4);  // 0..15
    const int kStart = z * KHALF;

    const u16* ga[8]; const u16* gb[8];
#pragma unroll
    for (int i = 0; i < 8; ++i) {
        int s  = i * 64 + lane;                     // 16B slot 0..511
        int r  = s >> 3;                            // pane row 0..63
        int sc = (s & 7) ^ (r & 7);                 // source k-chunk
        ga[i] = A + (size_t)(bm * 64 + r) * KTOT + kStart + sc * 8;
        gb[i] = B + (size_t)(bn * 64 + r) * KTOT + kStart + sc * 8;
    }

    f32x4 acc[4][4];
#pragma unroll
    for (int mt = 0; mt < 4; ++mt)
#pragma unroll
        for (int nt = 0; nt < 4; ++nt)
            acc[mt][nt] = (f32x4){0.f, 0.f, 0.f, 0.f};

    // stage iter 0 into buf 0 (16 DMA ops outstanding)
#pragma unroll
    for (int i = 0; i < 8; ++i) gl_lds16(ga[i], &lds[0][0][i * 512 + lane * 8]);
#pragma unroll
    for (int i = 0; i < 8; ++i) gl_lds16(gb[i], &lds[0][1][i * 512 + lane * 8]);

    const int nIter = KHALF / 64;                   // 72
    for (int it = 0; it < nIter; ++it) {
        const int cur = it & 1;
        if (it + 1 < nIter) {
            const int off = (it + 1) * 64;
            const int nxt = cur ^ 1;
#pragma unroll
            for (int i = 0; i < 8; ++i)
                gl_lds16(ga[i] + off, &lds[nxt][0][i * 512 + lane * 8]);
#pragma unroll
            for (int i = 0; i < 8; ++i)
                gl_lds16(gb[i] + off, &lds[nxt][1][i * 512 + lane * 8]);
            // 32 outstanding; wait for the 16 oldest (= current tile's DMA)
            __builtin_amdgcn_s_waitcnt(WAIT_VM16);
        } else {
            __builtin_amdgcn_s_waitcnt(WAIT_VM0);   // last tile: drain all
        }
        __builtin_amdgcn_sched_barrier(0);          // ds_reads must not hoist

#pragma unroll
        for (int kk = 0; kk < 2; ++kk) {
            short8_t af[4], bfg[4];
#pragma unroll
            for (int mt = 0; mt < 4; ++mt) {
                int row = mt * 16 + l15;
                int pc  = (kk * 4 + quad) ^ (row & 7);
                af[mt] = *(const short8_t*)(&lds[cur][0][(row * 8 + pc) * 8]);
            }
#pragma unroll
            for (int nt = 0; nt < 4; ++nt) {
                int row = nt * 16 + l15;
                int pc  = (kk * 4 + quad) ^ (row & 7);
                bfg[nt] = *(const short8_t*)(&lds[cur][1][(row * 8 + pc) * 8]);
            }
#pragma unroll
            for (int mt = 0; mt < 4; ++mt)
#pragma unroll
                for (int nt = 0; nt < 4; ++nt)
                    acc[mt][nt] = __builtin_amdgcn_mfma_f32_16x16x32_bf16(
                        af[mt], bfg[nt], acc[mt][nt], 0, 0, 0);
        }
    }

    // epilogue: C/D layout col = lane&15, row = quad*4 + reg  [m89-verified]
    float* C = P + (size_t)z * BATCH * ODIM;
#pragma unroll
    for (int mt = 0; mt < 4; ++mt) {
#pragma unroll
        for (int nt = 0; nt < 4; ++nt) {
            int row0 = bm * 64 + mt * 16 + quad * 4;
            int col  = bn * 64 + nt * 16 + l15;
#pragma unroll
            for (int r = 0; r < 4; ++r)
                C[(size_t)(row0 + r) * ODIM + col] = acc[mt][nt][r];
        }
    }
}

// out = P[0] + P[1]  (split-K reduction), float4 vectorized
__global__ void reduce_kernel(const float* __restrict__ P, float* __restrict__ out) {
    int t = blockIdx.x * 256 + threadIdx.x;
    f32x4 a = ((const f32x4*)P)[t];
    f32x4 b = ((const f32x4*)(P + (size_t)BATCH * ODIM))[t];
    ((f32x4*)out)[t] = a + b;
}

extern "C" void kernel_launch(void* const* d_in, const int* in_sizes, int n_in,
                              void* d_out, int out_size, void* d_ws, size_t ws_size,
                              hipStream_t stream) {
    const float* x      = (const float*)d_in[0];   // [4096,1024] f32
    const float* coeffs = (const float*)d_in[1];   // [1024,1024,9] f32
    float* out = (float*)d_out;                    // [4096,1024] f32

    u16* A  = (u16*)d_ws;                          // 75.5 MB
    u16* Bt = A + (size_t)BATCH * KTOT;            // 18.9 MB
    float* P = (float*)(Bt + (size_t)ODIM * KTOT); // 33.6 MB split-K partials

    prep_kernel<<<NB_B + NB_A, 256, 0, stream>>>(x, coeffs, A, Bt);
    gemm_kernel<<<2048, 64, 0, stream>>>(A, Bt, P);
    reduce_kernel<<<BATCH * ODIM / 1024, 256, 0, stream>>>(P, out);
}